// Round 1
// baseline (640.015 us; speedup 1.0000x reference)
//
#include <hip/hip_runtime.h>
#include <math.h>

#define WAVE 64
#define NEG_SLOPE 0.2f

// ---------------------------------------------------------------------------
// CSR build kernels (dst-sorted adjacency, self loops included)
// ---------------------------------------------------------------------------

__global__ __launch_bounds__(256) void init_cnt_kernel(int* cnt, int n) {
    int i = blockIdx.x * blockDim.x + threadIdx.x;
    if (i < n) cnt[i] = 1;  // self loop contributes 1 incoming edge per node
}

__global__ __launch_bounds__(256) void count_kernel(const int* __restrict__ dst,
                                                    int* cnt, int e) {
    int i = blockIdx.x * blockDim.x + threadIdx.x;
    if (i < e) atomicAdd(&cnt[dst[i]], 1);
}

// Single-block exclusive scan over cnt[n] -> rowptr[n+1], also fill[i]=rowptr[i]
__global__ __launch_bounds__(1024) void scan_kernel(const int* __restrict__ cnt,
                                                    int* __restrict__ rowptr,
                                                    int* __restrict__ fill, int n) {
    __shared__ int part[1024];
    int t = threadIdx.x;
    int seg = (n + 1023) / 1024;
    int lo = t * seg;
    int hi = min(lo + seg, n);
    int mysum = 0;
    for (int i = lo; i < hi; ++i) mysum += cnt[i];
    part[t] = mysum;
    __syncthreads();
    // Hillis-Steele inclusive scan
    for (int off = 1; off < 1024; off <<= 1) {
        int v = (t >= off) ? part[t - off] : 0;
        __syncthreads();
        part[t] += v;
        __syncthreads();
    }
    int run = part[t] - mysum;  // exclusive prefix of this thread's segment
    for (int i = lo; i < hi; ++i) {
        rowptr[i] = run;
        fill[i] = run;
        run += cnt[i];
    }
    if (t == 1023) rowptr[n] = part[1023];
}

__global__ __launch_bounds__(256) void scatter_kernel(const int* __restrict__ src,
                                                      const int* __restrict__ dst,
                                                      int* fill, int* __restrict__ csr_src,
                                                      int e, int n) {
    int i = blockIdx.x * blockDim.x + threadIdx.x;
    int total = e + n;
    if (i >= total) return;
    int s, d;
    if (i < e) { s = src[i]; d = dst[i]; }
    else       { s = i - e;  d = i - e;  }
    int pos = atomicAdd(&fill[d], 1);
    csr_src[pos] = s;
}

// ---------------------------------------------------------------------------
// Feature transform: H = X @ W ;  S = H . a_src ;  D = H . a_dst
// block = 256 threads = 4 waves; each wave handles one row at a time (lane=col)
// each block covers 64 rows; W staged in LDS.
// ---------------------------------------------------------------------------

template <int K>
__global__ __launch_bounds__(256) void gemm_feat_kernel(
    const float* __restrict__ X, const float* __restrict__ W,
    const float* __restrict__ a_s, const float* __restrict__ a_d,
    float* __restrict__ H, float* __restrict__ S, float* __restrict__ D, int n) {
    __shared__ float Wl[K * 64];
    int t = threadIdx.x;
    for (int i = t; i < K * 64; i += 256) Wl[i] = W[i];
    __syncthreads();
    int c  = t & 63;   // column / lane
    int rl = t >> 6;   // wave id within block: 0..3
    int base = blockIdx.x * 64;
    for (int rr = rl; rr < 64; rr += 4) {
        int row = base + rr;
        if (row >= n) break;
        const float* xr = X + (size_t)row * K;
        float acc = 0.f;
#pragma unroll 8
        for (int k = 0; k < K; ++k) acc = fmaf(xr[k], Wl[k * 64 + c], acc);
        H[(size_t)row * 64 + c] = acc;
        float vs = acc * a_s[c];
        float vd = acc * a_d[c];
        for (int o = 32; o; o >>= 1) {
            vs += __shfl_xor(vs, o);
            vd += __shfl_xor(vd, o);
        }
        if (c == 0) { S[row] = vs; D[row] = vd; }
    }
}

// ---------------------------------------------------------------------------
// GAT aggregation: per dst node i (one wave each):
//   e_j = leaky_relu(S[src_j] + D[i]);  softmax over incoming edges;
//   out[i,:] = sum_j coef_j * H[src_j,:] + bias  (optional relu)
// Online softmax across chunks of 64 edges; lanes=edges for logits,
// lanes=channels for accumulation (per-edge w/src broadcast via shfl).
// ---------------------------------------------------------------------------

__global__ __launch_bounds__(256) void gat_aggregate_kernel(
    const float* __restrict__ H, const float* __restrict__ S,
    const float* __restrict__ D, const int* __restrict__ rowptr,
    const int* __restrict__ csr_src, const float* __restrict__ bias,
    float* __restrict__ OUT, int n, int do_relu) {
    int wid  = (blockIdx.x * blockDim.x + threadIdx.x) >> 6;
    int lane = threadIdx.x & 63;
    if (wid >= n) return;
    int start = rowptr[wid];
    int end   = rowptr[wid + 1];
    float d_i = D[wid];

    float M = -INFINITY;  // running max
    float Z = 0.f;        // running exp-sum
    float acc = 0.f;      // per-channel accumulator (channel = lane)

    for (int cb = start; cb < end; cb += WAVE) {
        int j = cb + lane;
        int srcj = 0;
        float ej = -INFINITY;
        if (j < end) {
            srcj = csr_src[j];
            float e = S[srcj] + d_i;
            ej = (e > 0.f) ? e : NEG_SLOPE * e;
        }
        float mc = ej;
        for (int o = 32; o; o >>= 1) mc = fmaxf(mc, __shfl_xor(mc, o));
        float newM = fmaxf(M, mc);
        float scale = expf(M - newM);  // first iter: exp(-inf)=0
        float wj = (j < end) ? expf(ej - newM) : 0.f;
        float zc = wj;
        for (int o = 32; o; o >>= 1) zc += __shfl_xor(zc, o);
        Z = Z * scale + zc;
        acc *= scale;
        int nch = min(WAVE, end - cb);
        for (int tt = 0; tt < nch; ++tt) {
            float w  = __shfl(wj, tt);
            int   sv = __shfl(srcj, tt);
            acc = fmaf(w, H[(size_t)sv * 64 + lane], acc);
        }
        M = newM;
    }
    float o = acc / (Z + 1e-16f) + bias[lane];
    if (do_relu) o = fmaxf(o, 0.f);
    OUT[(size_t)wid * 64 + lane] = o;
}

// ---------------------------------------------------------------------------

static inline size_t align256(size_t x) { return (x + 255) & ~(size_t)255; }

extern "C" void kernel_launch(void* const* d_in, const int* in_sizes, int n_in,
                              void* d_out, int out_size, void* d_ws, size_t ws_size,
                              hipStream_t stream) {
    const float* x    = (const float*)d_in[0];
    const int*   esrc = (const int*)d_in[1];
    const int*   edst = (const int*)d_in[2];
    const int E = in_sizes[1];
    const int N = in_sizes[0] / 128;

    const float* W0 = (const float*)d_in[3];
    const float* as0 = (const float*)d_in[4];
    const float* ad0 = (const float*)d_in[5];
    const float* b0 = (const float*)d_in[6];
    const float* W1 = (const float*)d_in[7];
    const float* as1 = (const float*)d_in[8];
    const float* ad1 = (const float*)d_in[9];
    const float* b1 = (const float*)d_in[10];
    const float* W2 = (const float*)d_in[11];
    const float* as2 = (const float*)d_in[12];
    const float* ad2 = (const float*)d_in[13];
    const float* b2 = (const float*)d_in[14];

    // workspace layout
    char* p = (char*)d_ws;
    int* cnt     = (int*)p; p += align256((size_t)N * 4);
    int* rowptr  = (int*)p; p += align256((size_t)(N + 1) * 4);
    int* fill    = (int*)p; p += align256((size_t)N * 4);
    int* csr_src = (int*)p; p += align256((size_t)(E + N) * 4);
    float* h  = (float*)p; p += align256((size_t)N * 64 * 4);
    float* s  = (float*)p; p += align256((size_t)N * 4);
    float* d  = (float*)p; p += align256((size_t)N * 4);
    float* XA = (float*)p; p += align256((size_t)N * 64 * 4);
    float* XB = (float*)p; p += align256((size_t)N * 64 * 4);
    float* out = (float*)d_out;

    // ---- CSR build (once; shared by all 3 layers) ----
    init_cnt_kernel<<<(N + 255) / 256, 256, 0, stream>>>(cnt, N);
    count_kernel<<<(E + 255) / 256, 256, 0, stream>>>(edst, cnt, E);
    scan_kernel<<<1, 1024, 0, stream>>>(cnt, rowptr, fill, N);
    scatter_kernel<<<(E + N + 255) / 256, 256, 0, stream>>>(esrc, edst, fill, csr_src, E, N);

    int gemm_grid = (N + 63) / 64;
    int agg_grid  = (N + 3) / 4;  // 4 waves per 256-thread block, 1 wave per node

    // ---- layer 0: 128 -> 64, relu ----
    gemm_feat_kernel<128><<<gemm_grid, 256, 0, stream>>>(x, W0, as0, ad0, h, s, d, N);
    gat_aggregate_kernel<<<agg_grid, 256, 0, stream>>>(h, s, d, rowptr, csr_src, b0, XA, N, 1);

    // ---- layer 1: 64 -> 64, relu ----
    gemm_feat_kernel<64><<<gemm_grid, 256, 0, stream>>>(XA, W1, as1, ad1, h, s, d, N);
    gat_aggregate_kernel<<<agg_grid, 256, 0, stream>>>(h, s, d, rowptr, csr_src, b1, XB, N, 1);

    // ---- layer 2: 64 -> 64, no relu ----
    gemm_feat_kernel<64><<<gemm_grid, 256, 0, stream>>>(XB, W2, as2, ad2, h, s, d, N);
    gat_aggregate_kernel<<<agg_grid, 256, 0, stream>>>(h, s, d, rowptr, csr_src, b2, out, N, 0);
}

// Round 2
// 544.405 us; speedup vs baseline: 1.1756x; 1.1756x over previous
//
#include <hip/hip_runtime.h>
#include <math.h>

#define WAVE 64
#define NEG_SLOPE 0.2f

// ---------------------------------------------------------------------------
// CSR build kernels (dst-sorted adjacency, self loops included)
// ---------------------------------------------------------------------------

__global__ __launch_bounds__(256) void init_cnt_kernel(int* cnt, int n) {
    int i = blockIdx.x * blockDim.x + threadIdx.x;
    if (i < n) cnt[i] = 1;  // self loop contributes 1 incoming edge per node
}

__global__ __launch_bounds__(256) void count_kernel(const int* __restrict__ dst,
                                                    int* cnt, int e) {
    int i = blockIdx.x * blockDim.x + threadIdx.x;
    if (i < e) atomicAdd(&cnt[dst[i]], 1);
}

// ---- device-wide exclusive scan, 3 kernels --------------------------------
// A: per-block (256 elems) sums -> blocksums[B]
__global__ __launch_bounds__(256) void scan_partial_kernel(const int* __restrict__ cnt,
                                                           int* __restrict__ blocksums,
                                                           int n) {
    __shared__ int ws[4];
    int i = blockIdx.x * 256 + threadIdx.x;
    int v = (i < n) ? cnt[i] : 0;
    int s = v;
    for (int o = 32; o; o >>= 1) s += __shfl_xor(s, o);
    int lane = threadIdx.x & 63, w = threadIdx.x >> 6;
    if (lane == 0) ws[w] = s;
    __syncthreads();
    if (threadIdx.x == 0)
        blocksums[blockIdx.x] = ws[0] + ws[1] + ws[2] + ws[3];
}

// B: one block scans blocksums[B] (B <= 1024) -> exclusive blockoff[B], rowptr[n]=total
__global__ __launch_bounds__(1024) void scan_blocksums_kernel(int* __restrict__ blocksums,
                                                              int* __restrict__ rowptr,
                                                              int nblocks, int n) {
    __shared__ int sh[1024];
    int t = threadIdx.x;
    int v = (t < nblocks) ? blocksums[t] : 0;
    sh[t] = v;
    __syncthreads();
    for (int off = 1; off < 1024; off <<= 1) {
        int u = (t >= off) ? sh[t - off] : 0;
        __syncthreads();
        sh[t] += u;
        __syncthreads();
    }
    if (t < nblocks) blocksums[t] = sh[t] - v;  // exclusive
    if (t == 1023) rowptr[n] = sh[1023];        // total
}

// C: per-block exclusive scan of 256 elems + block offset; write rowptr & fill
__global__ __launch_bounds__(256) void scan_write_kernel(const int* __restrict__ cnt,
                                                         const int* __restrict__ blocksums,
                                                         int* __restrict__ rowptr,
                                                         int* __restrict__ fill, int n) {
    __shared__ int sh[256];
    int t = threadIdx.x;
    int i = blockIdx.x * 256 + t;
    int v = (i < n) ? cnt[i] : 0;
    sh[t] = v;
    __syncthreads();
    for (int off = 1; off < 256; off <<= 1) {
        int u = (t >= off) ? sh[t - off] : 0;
        __syncthreads();
        sh[t] += u;
        __syncthreads();
    }
    if (i < n) {
        int ex = sh[t] - v + blocksums[blockIdx.x];
        rowptr[i] = ex;
        fill[i] = ex;
    }
}

__global__ __launch_bounds__(256) void scatter_kernel(const int* __restrict__ src,
                                                      const int* __restrict__ dst,
                                                      int* fill, int* __restrict__ csr_src,
                                                      int e, int n) {
    int i = blockIdx.x * blockDim.x + threadIdx.x;
    int total = e + n;
    if (i >= total) return;
    int s, d;
    if (i < e) { s = src[i]; d = dst[i]; }
    else       { s = i - e;  d = i - e;  }
    int pos = atomicAdd(&fill[d], 1);
    csr_src[pos] = s;
}

// ---------------------------------------------------------------------------
// Feature transform: H = X @ W ;  S = H . a_src ;  D = H . a_dst
// block = 256 threads = 4 waves; each wave handles one row at a time (lane=col)
// each block covers 64 rows; W staged in LDS.
// ---------------------------------------------------------------------------

template <int K>
__global__ __launch_bounds__(256) void gemm_feat_kernel(
    const float* __restrict__ X, const float* __restrict__ W,
    const float* __restrict__ a_s, const float* __restrict__ a_d,
    float* __restrict__ H, float* __restrict__ S, float* __restrict__ D, int n) {
    __shared__ float Wl[K * 64];
    int t = threadIdx.x;
    for (int i = t; i < K * 64; i += 256) Wl[i] = W[i];
    __syncthreads();
    int c  = t & 63;   // column / lane
    int rl = t >> 6;   // wave id within block: 0..3
    int base = blockIdx.x * 64;
    for (int rr = rl; rr < 64; rr += 4) {
        int row = base + rr;
        if (row >= n) break;
        const float* xr = X + (size_t)row * K;
        float acc = 0.f;
#pragma unroll 8
        for (int k = 0; k < K; ++k) acc = fmaf(xr[k], Wl[k * 64 + c], acc);
        H[(size_t)row * 64 + c] = acc;
        float vs = acc * a_s[c];
        float vd = acc * a_d[c];
        for (int o = 32; o; o >>= 1) {
            vs += __shfl_xor(vs, o);
            vd += __shfl_xor(vd, o);
        }
        if (c == 0) { S[row] = vs; D[row] = vd; }
    }
}

// ---------------------------------------------------------------------------
// GAT aggregation: per dst node i (one wave each):
//   e_j = leaky_relu(S[src_j] + D[i]);  softmax over incoming edges;
//   out[i,:] = sum_j coef_j * H[src_j,:] + bias  (optional relu)
// Online softmax across chunks of 64 edges; lanes=edges for logits,
// lanes=channels for accumulation (per-edge w/src broadcast via shfl).
// ---------------------------------------------------------------------------

__global__ __launch_bounds__(256) void gat_aggregate_kernel(
    const float* __restrict__ H, const float* __restrict__ S,
    const float* __restrict__ D, const int* __restrict__ rowptr,
    const int* __restrict__ csr_src, const float* __restrict__ bias,
    float* __restrict__ OUT, int n, int do_relu) {
    int wid  = (blockIdx.x * blockDim.x + threadIdx.x) >> 6;
    int lane = threadIdx.x & 63;
    if (wid >= n) return;
    int start = rowptr[wid];
    int end   = rowptr[wid + 1];
    float d_i = D[wid];

    float M = -INFINITY;  // running max
    float Z = 0.f;        // running exp-sum
    float acc = 0.f;      // per-channel accumulator (channel = lane)

    for (int cb = start; cb < end; cb += WAVE) {
        int j = cb + lane;
        int srcj = 0;
        float ej = -INFINITY;
        if (j < end) {
            srcj = csr_src[j];
            float e = S[srcj] + d_i;
            ej = (e > 0.f) ? e : NEG_SLOPE * e;
        }
        float mc = ej;
        for (int o = 32; o; o >>= 1) mc = fmaxf(mc, __shfl_xor(mc, o));
        float newM = fmaxf(M, mc);
        float scale = expf(M - newM);  // first iter: exp(-inf)=0
        float wj = (j < end) ? expf(ej - newM) : 0.f;
        float zc = wj;
        for (int o = 32; o; o >>= 1) zc += __shfl_xor(zc, o);
        Z = Z * scale + zc;
        acc *= scale;
        int nch = min(WAVE, end - cb);
        for (int tt = 0; tt < nch; ++tt) {
            float w  = __shfl(wj, tt);
            int   sv = __shfl(srcj, tt);
            acc = fmaf(w, H[(size_t)sv * 64 + lane], acc);
        }
        M = newM;
    }
    float o = acc / (Z + 1e-16f) + bias[lane];
    if (do_relu) o = fmaxf(o, 0.f);
    OUT[(size_t)wid * 64 + lane] = o;
}

// ---------------------------------------------------------------------------

static inline size_t align256(size_t x) { return (x + 255) & ~(size_t)255; }

extern "C" void kernel_launch(void* const* d_in, const int* in_sizes, int n_in,
                              void* d_out, int out_size, void* d_ws, size_t ws_size,
                              hipStream_t stream) {
    const float* x    = (const float*)d_in[0];
    const int*   esrc = (const int*)d_in[1];
    const int*   edst = (const int*)d_in[2];
    const int E = in_sizes[1];
    const int N = in_sizes[0] / 128;

    const float* W0 = (const float*)d_in[3];
    const float* as0 = (const float*)d_in[4];
    const float* ad0 = (const float*)d_in[5];
    const float* b0 = (const float*)d_in[6];
    const float* W1 = (const float*)d_in[7];
    const float* as1 = (const float*)d_in[8];
    const float* ad1 = (const float*)d_in[9];
    const float* b1 = (const float*)d_in[10];
    const float* W2 = (const float*)d_in[11];
    const float* as2 = (const float*)d_in[12];
    const float* ad2 = (const float*)d_in[13];
    const float* b2 = (const float*)d_in[14];

    // workspace layout
    char* p = (char*)d_ws;
    int* cnt       = (int*)p; p += align256((size_t)N * 4);
    int* rowptr    = (int*)p; p += align256((size_t)(N + 1) * 4);
    int* fill      = (int*)p; p += align256((size_t)N * 4);
    int* blocksums = (int*)p; p += align256(1024 * 4);
    int* csr_src   = (int*)p; p += align256((size_t)(E + N) * 4);
    float* h  = (float*)p; p += align256((size_t)N * 64 * 4);
    float* s  = (float*)p; p += align256((size_t)N * 4);
    float* d  = (float*)p; p += align256((size_t)N * 4);
    float* XA = (float*)p; p += align256((size_t)N * 64 * 4);
    float* XB = (float*)p; p += align256((size_t)N * 64 * 4);
    float* out = (float*)d_out;

    // ---- CSR build (once; shared by all 3 layers) ----
    int nscan = (N + 255) / 256;  // 196 blocks <= 1024
    init_cnt_kernel<<<(N + 255) / 256, 256, 0, stream>>>(cnt, N);
    count_kernel<<<(E + 255) / 256, 256, 0, stream>>>(edst, cnt, E);
    scan_partial_kernel<<<nscan, 256, 0, stream>>>(cnt, blocksums, N);
    scan_blocksums_kernel<<<1, 1024, 0, stream>>>(blocksums, rowptr, nscan, N);
    scan_write_kernel<<<nscan, 256, 0, stream>>>(cnt, blocksums, rowptr, fill, N);
    scatter_kernel<<<(E + N + 255) / 256, 256, 0, stream>>>(esrc, edst, fill, csr_src, E, N);

    int gemm_grid = (N + 63) / 64;
    int agg_grid  = (N + 3) / 4;  // 4 waves per 256-thread block, 1 wave per node

    // ---- layer 0: 128 -> 64, relu ----
    gemm_feat_kernel<128><<<gemm_grid, 256, 0, stream>>>(x, W0, as0, ad0, h, s, d, N);
    gat_aggregate_kernel<<<agg_grid, 256, 0, stream>>>(h, s, d, rowptr, csr_src, b0, XA, N, 1);

    // ---- layer 1: 64 -> 64, relu ----
    gemm_feat_kernel<64><<<gemm_grid, 256, 0, stream>>>(XA, W1, as1, ad1, h, s, d, N);
    gat_aggregate_kernel<<<agg_grid, 256, 0, stream>>>(h, s, d, rowptr, csr_src, b1, XB, N, 1);

    // ---- layer 2: 64 -> 64, no relu ----
    gemm_feat_kernel<64><<<gemm_grid, 256, 0, stream>>>(XB, W2, as2, ad2, h, s, d, N);
    gat_aggregate_kernel<<<agg_grid, 256, 0, stream>>>(h, s, d, rowptr, csr_src, b2, out, N, 0);
}

// Round 3
// 429.458 us; speedup vs baseline: 1.4903x; 1.2677x over previous
//
#include <hip/hip_runtime.h>
#include <math.h>

#define WAVE 64
#define NEG_SLOPE 0.2f

// ---------------------------------------------------------------------------
// CSR build kernels (dst-sorted adjacency, self loops included)
// ---------------------------------------------------------------------------

__global__ __launch_bounds__(256) void init_cnt_kernel(int* cnt, int n) {
    int i = blockIdx.x * blockDim.x + threadIdx.x;
    if (i < n) cnt[i] = 1;  // self loop contributes 1 incoming edge per node
}

__global__ __launch_bounds__(256) void count_kernel(const int* __restrict__ dst,
                                                    int* cnt, int e) {
    int i = blockIdx.x * blockDim.x + threadIdx.x;
    if (i < e) atomicAdd(&cnt[dst[i]], 1);
}

// ---- device-wide exclusive scan, 3 kernels --------------------------------
__global__ __launch_bounds__(256) void scan_partial_kernel(const int* __restrict__ cnt,
                                                           int* __restrict__ blocksums,
                                                           int n) {
    __shared__ int ws[4];
    int i = blockIdx.x * 256 + threadIdx.x;
    int v = (i < n) ? cnt[i] : 0;
    int s = v;
    for (int o = 32; o; o >>= 1) s += __shfl_xor(s, o);
    int lane = threadIdx.x & 63, w = threadIdx.x >> 6;
    if (lane == 0) ws[w] = s;
    __syncthreads();
    if (threadIdx.x == 0)
        blocksums[blockIdx.x] = ws[0] + ws[1] + ws[2] + ws[3];
}

__global__ __launch_bounds__(1024) void scan_blocksums_kernel(int* __restrict__ blocksums,
                                                              int* __restrict__ rowptr,
                                                              int nblocks, int n) {
    __shared__ int sh[1024];
    int t = threadIdx.x;
    int v = (t < nblocks) ? blocksums[t] : 0;
    sh[t] = v;
    __syncthreads();
    for (int off = 1; off < 1024; off <<= 1) {
        int u = (t >= off) ? sh[t - off] : 0;
        __syncthreads();
        sh[t] += u;
        __syncthreads();
    }
    if (t < nblocks) blocksums[t] = sh[t] - v;  // exclusive
    if (t == 1023) rowptr[n] = sh[1023];        // total
}

__global__ __launch_bounds__(256) void scan_write_kernel(const int* __restrict__ cnt,
                                                         const int* __restrict__ blocksums,
                                                         int* __restrict__ rowptr,
                                                         int* __restrict__ fill, int n) {
    __shared__ int sh[256];
    int t = threadIdx.x;
    int i = blockIdx.x * 256 + t;
    int v = (i < n) ? cnt[i] : 0;
    sh[t] = v;
    __syncthreads();
    for (int off = 1; off < 256; off <<= 1) {
        int u = (t >= off) ? sh[t - off] : 0;
        __syncthreads();
        sh[t] += u;
        __syncthreads();
    }
    if (i < n) {
        int ex = sh[t] - v + blocksums[blockIdx.x];
        rowptr[i] = ex;
        fill[i] = ex;
    }
}

__global__ __launch_bounds__(256) void scatter_kernel(const int* __restrict__ src,
                                                      const int* __restrict__ dst,
                                                      int* fill, int* __restrict__ csr_src,
                                                      int e, int n) {
    int i = blockIdx.x * blockDim.x + threadIdx.x;
    int total = e + n;
    if (i >= total) return;
    int s, d;
    if (i < e) { s = src[i]; d = dst[i]; }
    else       { s = i - e;  d = i - e;  }
    int pos = atomicAdd(&fill[d], 1);
    csr_src[pos] = s;
}

// ---------------------------------------------------------------------------
// Feature transform: H = X @ W ;  S = H . a_src ;  D = H . a_dst
// Register-tiled: 256 threads = 16(tx: col groups) x 16(ty: row groups),
// each thread computes a 4x4 micro-tile of the 64x64 output tile.
// Per k: 4 broadcast ds_read_b32 (X) + 1 ds_read_b128 (W) + 16 fma.
// Row strides padded to 68 dwords: b128-aligned, bank-conflict <= 2-way (free).
// ---------------------------------------------------------------------------

template <int K>
__global__ __launch_bounds__(256) void gemm_feat_kernel(
    const float* __restrict__ X, const float* __restrict__ W,
    const float* __restrict__ a_s, const float* __restrict__ a_d,
    float* __restrict__ H, float* __restrict__ S, float* __restrict__ D, int n) {
    constexpr int LSTR = 68;  // padded row stride (dwords)
    __shared__ float Xs[64 * LSTR];
    __shared__ float Ws[64 * LSTR];
    int t = threadIdx.x;
    int tx = t & 15;   // col group: cols 4tx..4tx+3
    int ty = t >> 4;   // row group: rows 4ty..4ty+3
    int base = blockIdx.x * 64;
    float acc[4][4] = {};

    int q = t & 3;        // staging quarter
    int srow = t >> 2;    // staging row 0..63

    for (int k0 = 0; k0 < K; k0 += 64) {
        int grow = base + srow;
#pragma unroll
        for (int j = 0; j < 4; ++j) {
            int c = 16 * j + 4 * q;
            float4 v = make_float4(0.f, 0.f, 0.f, 0.f);
            if (grow < n) v = *(const float4*)(X + (size_t)grow * K + k0 + c);
            *(float4*)(Xs + srow * LSTR + c) = v;
            float4 w = *(const float4*)(W + (size_t)(k0 + srow) * 64 + c);
            *(float4*)(Ws + srow * LSTR + c) = w;
        }
        __syncthreads();
#pragma unroll 8
        for (int kk = 0; kk < 64; ++kk) {
            float4 wv = *(const float4*)(Ws + kk * LSTR + 4 * tx);
#pragma unroll
            for (int i = 0; i < 4; ++i) {
                float xv = Xs[(4 * ty + i) * LSTR + kk];
                acc[i][0] = fmaf(xv, wv.x, acc[i][0]);
                acc[i][1] = fmaf(xv, wv.y, acc[i][1]);
                acc[i][2] = fmaf(xv, wv.z, acc[i][2]);
                acc[i][3] = fmaf(xv, wv.w, acc[i][3]);
            }
        }
        __syncthreads();
    }

    // epilogue: store H rows + reduce S/D logits across the 16 tx lanes
    const float4 av_s = *(const float4*)(a_s + 4 * tx);
    const float4 av_d = *(const float4*)(a_d + 4 * tx);
#pragma unroll
    for (int i = 0; i < 4; ++i) {
        int row = base + 4 * ty + i;
        bool ok = row < n;
        if (ok) {
            float4 hv = make_float4(acc[i][0], acc[i][1], acc[i][2], acc[i][3]);
            *(float4*)(H + (size_t)row * 64 + 4 * tx) = hv;
        }
        float ps = acc[i][0] * av_s.x + acc[i][1] * av_s.y +
                   acc[i][2] * av_s.z + acc[i][3] * av_s.w;
        float pd = acc[i][0] * av_d.x + acc[i][1] * av_d.y +
                   acc[i][2] * av_d.z + acc[i][3] * av_d.w;
        for (int o = 1; o < 16; o <<= 1) {
            ps += __shfl_xor(ps, o);
            pd += __shfl_xor(pd, o);
        }
        if (tx == 0 && ok) { S[row] = ps; D[row] = pd; }
    }
}

// ---------------------------------------------------------------------------
// GAT aggregation: per dst node i (one wave each):
//   e_j = leaky_relu(S[src_j] + D[i]);  softmax over incoming edges;
//   out[i,:] = sum_j coef_j * H[src_j,:] + bias  (optional relu)
// ---------------------------------------------------------------------------

__global__ __launch_bounds__(256) void gat_aggregate_kernel(
    const float* __restrict__ H, const float* __restrict__ S,
    const float* __restrict__ D, const int* __restrict__ rowptr,
    const int* __restrict__ csr_src, const float* __restrict__ bias,
    float* __restrict__ OUT, int n, int do_relu) {
    int wid  = (blockIdx.x * blockDim.x + threadIdx.x) >> 6;
    int lane = threadIdx.x & 63;
    if (wid >= n) return;
    int start = rowptr[wid];
    int end   = rowptr[wid + 1];
    float d_i = D[wid];

    float M = -INFINITY;  // running max
    float Z = 0.f;        // running exp-sum
    float acc = 0.f;      // per-channel accumulator (channel = lane)

    for (int cb = start; cb < end; cb += WAVE) {
        int j = cb + lane;
        int srcj = 0;
        float ej = -INFINITY;
        if (j < end) {
            srcj = csr_src[j];
            float e = S[srcj] + d_i;
            ej = (e > 0.f) ? e : NEG_SLOPE * e;
        }
        float mc = ej;
        for (int o = 32; o; o >>= 1) mc = fmaxf(mc, __shfl_xor(mc, o));
        float newM = fmaxf(M, mc);
        float scale = expf(M - newM);  // first iter: exp(-inf)=0
        float wj = (j < end) ? expf(ej - newM) : 0.f;
        float zc = wj;
        for (int o = 32; o; o >>= 1) zc += __shfl_xor(zc, o);
        Z = Z * scale + zc;
        acc *= scale;
        int nch = min(WAVE, end - cb);
        for (int tt = 0; tt < nch; ++tt) {
            float w  = __shfl(wj, tt);
            int   sv = __shfl(srcj, tt);
            acc = fmaf(w, H[(size_t)sv * 64 + lane], acc);
        }
        M = newM;
    }
    float o = acc / (Z + 1e-16f) + bias[lane];
    if (do_relu) o = fmaxf(o, 0.f);
    OUT[(size_t)wid * 64 + lane] = o;
}

// ---------------------------------------------------------------------------

static inline size_t align256(size_t x) { return (x + 255) & ~(size_t)255; }

extern "C" void kernel_launch(void* const* d_in, const int* in_sizes, int n_in,
                              void* d_out, int out_size, void* d_ws, size_t ws_size,
                              hipStream_t stream) {
    const float* x    = (const float*)d_in[0];
    const int*   esrc = (const int*)d_in[1];
    const int*   edst = (const int*)d_in[2];
    const int E = in_sizes[1];
    const int N = in_sizes[0] / 128;

    const float* W0 = (const float*)d_in[3];
    const float* as0 = (const float*)d_in[4];
    const float* ad0 = (const float*)d_in[5];
    const float* b0 = (const float*)d_in[6];
    const float* W1 = (const float*)d_in[7];
    const float* as1 = (const float*)d_in[8];
    const float* ad1 = (const float*)d_in[9];
    const float* b1 = (const float*)d_in[10];
    const float* W2 = (const float*)d_in[11];
    const float* as2 = (const float*)d_in[12];
    const float* ad2 = (const float*)d_in[13];
    const float* b2 = (const float*)d_in[14];

    // workspace layout
    char* p = (char*)d_ws;
    int* cnt       = (int*)p; p += align256((size_t)N * 4);
    int* rowptr    = (int*)p; p += align256((size_t)(N + 1) * 4);
    int* fill      = (int*)p; p += align256((size_t)N * 4);
    int* blocksums = (int*)p; p += align256(1024 * 4);
    int* csr_src   = (int*)p; p += align256((size_t)(E + N) * 4);
    float* h  = (float*)p; p += align256((size_t)N * 64 * 4);
    float* s  = (float*)p; p += align256((size_t)N * 4);
    float* d  = (float*)p; p += align256((size_t)N * 4);
    float* XA = (float*)p; p += align256((size_t)N * 64 * 4);
    float* XB = (float*)p; p += align256((size_t)N * 64 * 4);
    float* out = (float*)d_out;

    // ---- CSR build (once; shared by all 3 layers) ----
    int nscan = (N + 255) / 256;  // 196 blocks <= 1024
    init_cnt_kernel<<<(N + 255) / 256, 256, 0, stream>>>(cnt, N);
    count_kernel<<<(E + 255) / 256, 256, 0, stream>>>(edst, cnt, E);
    scan_partial_kernel<<<nscan, 256, 0, stream>>>(cnt, blocksums, N);
    scan_blocksums_kernel<<<1, 1024, 0, stream>>>(blocksums, rowptr, nscan, N);
    scan_write_kernel<<<nscan, 256, 0, stream>>>(cnt, blocksums, rowptr, fill, N);
    scatter_kernel<<<(E + N + 255) / 256, 256, 0, stream>>>(esrc, edst, fill, csr_src, E, N);

    int gemm_grid = (N + 63) / 64;
    int agg_grid  = (N + 3) / 4;  // 4 waves per 256-thread block, 1 wave per node

    // ---- layer 0: 128 -> 64, relu ----
    gemm_feat_kernel<128><<<gemm_grid, 256, 0, stream>>>(x, W0, as0, ad0, h, s, d, N);
    gat_aggregate_kernel<<<agg_grid, 256, 0, stream>>>(h, s, d, rowptr, csr_src, b0, XA, N, 1);

    // ---- layer 1: 64 -> 64, relu ----
    gemm_feat_kernel<64><<<gemm_grid, 256, 0, stream>>>(XA, W1, as1, ad1, h, s, d, N);
    gat_aggregate_kernel<<<agg_grid, 256, 0, stream>>>(h, s, d, rowptr, csr_src, b1, XB, N, 1);

    // ---- layer 2: 64 -> 64, no relu ----
    gemm_feat_kernel<64><<<gemm_grid, 256, 0, stream>>>(XB, W2, as2, ad2, h, s, d, N);
    gat_aggregate_kernel<<<agg_grid, 256, 0, stream>>>(h, s, d, rowptr, csr_src, b2, out, N, 0);
}

// Round 4
// 358.172 us; speedup vs baseline: 1.7869x; 1.1990x over previous
//
#include <hip/hip_runtime.h>
#include <math.h>

#define WAVE 64
#define NEG_SLOPE 0.2f

// ---------------------------------------------------------------------------
// CSR build kernels (dst-sorted adjacency, self loops included)
// ---------------------------------------------------------------------------

__global__ __launch_bounds__(256) void init_cnt_kernel(int* cnt, int n) {
    int i = blockIdx.x * blockDim.x + threadIdx.x;
    if (i < n) cnt[i] = 1;  // self loop contributes 1 incoming edge per node
}

__global__ __launch_bounds__(256) void count_kernel(const int* __restrict__ dst,
                                                    int* cnt, int e) {
    int i = blockIdx.x * blockDim.x + threadIdx.x;
    if (i < e) atomicAdd(&cnt[dst[i]], 1);
}

// ---- device-wide exclusive scan, 3 kernels --------------------------------
__global__ __launch_bounds__(256) void scan_partial_kernel(const int* __restrict__ cnt,
                                                           int* __restrict__ blocksums,
                                                           int n) {
    __shared__ int ws[4];
    int i = blockIdx.x * 256 + threadIdx.x;
    int v = (i < n) ? cnt[i] : 0;
    int s = v;
    for (int o = 32; o; o >>= 1) s += __shfl_xor(s, o);
    int lane = threadIdx.x & 63, w = threadIdx.x >> 6;
    if (lane == 0) ws[w] = s;
    __syncthreads();
    if (threadIdx.x == 0)
        blocksums[blockIdx.x] = ws[0] + ws[1] + ws[2] + ws[3];
}

__global__ __launch_bounds__(1024) void scan_blocksums_kernel(int* __restrict__ blocksums,
                                                              int* __restrict__ rowptr,
                                                              int nblocks, int n) {
    __shared__ int sh[1024];
    int t = threadIdx.x;
    int v = (t < nblocks) ? blocksums[t] : 0;
    sh[t] = v;
    __syncthreads();
    for (int off = 1; off < 1024; off <<= 1) {
        int u = (t >= off) ? sh[t - off] : 0;
        __syncthreads();
        sh[t] += u;
        __syncthreads();
    }
    if (t < nblocks) blocksums[t] = sh[t] - v;  // exclusive
    if (t == 1023) rowptr[n] = sh[1023];        // total
}

__global__ __launch_bounds__(256) void scan_write_kernel(const int* __restrict__ cnt,
                                                         const int* __restrict__ blocksums,
                                                         int* __restrict__ rowptr,
                                                         int* __restrict__ fill, int n) {
    __shared__ int sh[256];
    int t = threadIdx.x;
    int i = blockIdx.x * 256 + t;
    int v = (i < n) ? cnt[i] : 0;
    sh[t] = v;
    __syncthreads();
    for (int off = 1; off < 256; off <<= 1) {
        int u = (t >= off) ? sh[t - off] : 0;
        __syncthreads();
        sh[t] += u;
        __syncthreads();
    }
    if (i < n) {
        int ex = sh[t] - v + blocksums[blockIdx.x];
        rowptr[i] = ex;
        fill[i] = ex;
    }
}

__global__ __launch_bounds__(256) void scatter_kernel(const int* __restrict__ src,
                                                      const int* __restrict__ dst,
                                                      int* fill, int* __restrict__ csr_src,
                                                      int e, int n) {
    int i = blockIdx.x * blockDim.x + threadIdx.x;
    int total = e + n;
    if (i >= total) return;
    int s, d;
    if (i < e) { s = src[i]; d = dst[i]; }
    else       { s = i - e;  d = i - e;  }
    int pos = atomicAdd(&fill[d], 1);
    csr_src[pos] = s;
}

// ---------------------------------------------------------------------------
// Feature transform: H = X @ W ;  S = H . a_src ;  D = H . a_dst
// Register-tiled: 256 threads = 16x16, 4x4 micro-tile per thread.
// ---------------------------------------------------------------------------

template <int K>
__global__ __launch_bounds__(256) void gemm_feat_kernel(
    const float* __restrict__ X, const float* __restrict__ W,
    const float* __restrict__ a_s, const float* __restrict__ a_d,
    float* __restrict__ H, float* __restrict__ S, float* __restrict__ D, int n) {
    constexpr int LSTR = 68;  // padded row stride (dwords)
    __shared__ float Xs[64 * LSTR];
    __shared__ float Ws[64 * LSTR];
    int t = threadIdx.x;
    int tx = t & 15;   // col group: cols 4tx..4tx+3
    int ty = t >> 4;   // row group: rows 4ty..4ty+3
    int base = blockIdx.x * 64;
    float acc[4][4] = {};

    int q = t & 3;        // staging quarter
    int srow = t >> 2;    // staging row 0..63

    for (int k0 = 0; k0 < K; k0 += 64) {
        int grow = base + srow;
#pragma unroll
        for (int j = 0; j < 4; ++j) {
            int c = 16 * j + 4 * q;
            float4 v = make_float4(0.f, 0.f, 0.f, 0.f);
            if (grow < n) v = *(const float4*)(X + (size_t)grow * K + k0 + c);
            *(float4*)(Xs + srow * LSTR + c) = v;
            float4 w = *(const float4*)(W + (size_t)(k0 + srow) * 64 + c);
            *(float4*)(Ws + srow * LSTR + c) = w;
        }
        __syncthreads();
#pragma unroll 8
        for (int kk = 0; kk < 64; ++kk) {
            float4 wv = *(const float4*)(Ws + kk * LSTR + 4 * tx);
#pragma unroll
            for (int i = 0; i < 4; ++i) {
                float xv = Xs[(4 * ty + i) * LSTR + kk];
                acc[i][0] = fmaf(xv, wv.x, acc[i][0]);
                acc[i][1] = fmaf(xv, wv.y, acc[i][1]);
                acc[i][2] = fmaf(xv, wv.z, acc[i][2]);
                acc[i][3] = fmaf(xv, wv.w, acc[i][3]);
            }
        }
        __syncthreads();
    }

    // epilogue: store H rows + reduce S/D logits across the 16 tx lanes
    const float4 av_s = *(const float4*)(a_s + 4 * tx);
    const float4 av_d = *(const float4*)(a_d + 4 * tx);
#pragma unroll
    for (int i = 0; i < 4; ++i) {
        int row = base + 4 * ty + i;
        bool ok = row < n;
        if (ok) {
            float4 hv = make_float4(acc[i][0], acc[i][1], acc[i][2], acc[i][3]);
            *(float4*)(H + (size_t)row * 64 + 4 * tx) = hv;
        }
        float ps = acc[i][0] * av_s.x + acc[i][1] * av_s.y +
                   acc[i][2] * av_s.z + acc[i][3] * av_s.w;
        float pd = acc[i][0] * av_d.x + acc[i][1] * av_d.y +
                   acc[i][2] * av_d.z + acc[i][3] * av_d.w;
        for (int o = 1; o < 16; o <<= 1) {
            ps += __shfl_xor(ps, o);
            pd += __shfl_xor(pd, o);
        }
        if (tx == 0 && ok) { S[row] = ps; D[row] = pd; }
    }
}

// ---------------------------------------------------------------------------
// GAT aggregation, one wave per dst node.
// Logit phase: lane = edge (chunk of 64), online softmax.
// Row phase: wave split into 4 edge-subgroups x 16 channel-groups;
// per iteration 4 rows are gathered in parallel, 16 B (float4) per lane.
// Final: cross-subgroup reduce (shfl_xor 16/32), float4 store.
// ---------------------------------------------------------------------------

__global__ __launch_bounds__(256) void gat_aggregate_kernel(
    const float* __restrict__ H, const float* __restrict__ S,
    const float* __restrict__ D, const int* __restrict__ rowptr,
    const int* __restrict__ csr_src, const float* __restrict__ bias,
    float* __restrict__ OUT, int n, int do_relu) {
    int wid  = (blockIdx.x * blockDim.x + threadIdx.x) >> 6;
    int lane = threadIdx.x & 63;
    if (wid >= n) return;
    int eg = lane >> 4;   // edge subgroup 0..3
    int cg = lane & 15;   // channel group: channels 4cg..4cg+3
    int start = rowptr[wid];
    int end   = rowptr[wid + 1];
    float d_i = D[wid];

    float M = -INFINITY;
    float Z = 0.f;
    float4 acc = make_float4(0.f, 0.f, 0.f, 0.f);

    for (int cb = start; cb < end; cb += WAVE) {
        int j = cb + lane;
        int srcj = 0;
        float ej = -INFINITY;
        if (j < end) {
            srcj = csr_src[j];
            float e = S[srcj] + d_i;
            ej = (e > 0.f) ? e : NEG_SLOPE * e;
        }
        float mc = ej;
        for (int o = 32; o; o >>= 1) mc = fmaxf(mc, __shfl_xor(mc, o));
        float newM = fmaxf(M, mc);
        float scale = expf(M - newM);  // first iter: exp(-inf)=0
        float wj = (j < end) ? expf(ej - newM) : 0.f;
        float zc = wj;
        for (int o = 32; o; o >>= 1) zc += __shfl_xor(zc, o);
        Z = Z * scale + zc;
        acc.x *= scale; acc.y *= scale; acc.z *= scale; acc.w *= scale;
        M = newM;

        int nch = min(WAVE, end - cb);
        for (int c0 = 0; c0 < nch; c0 += 4) {
            int c = c0 + eg;  // edge slot within chunk, always a valid lane idx
            float w  = __shfl(wj, c);
            int   sv = __shfl(srcj, c);
            if (c < nch) {
                float4 hv = *(const float4*)(H + (size_t)sv * 64 + 4 * cg);
                acc.x = fmaf(w, hv.x, acc.x);
                acc.y = fmaf(w, hv.y, acc.y);
                acc.z = fmaf(w, hv.z, acc.z);
                acc.w = fmaf(w, hv.w, acc.w);
            }
        }
    }

    // reduce across the 4 edge subgroups (lanes l, l^16, l^32, l^48)
    for (int o = 16; o < 64; o <<= 1) {
        acc.x += __shfl_xor(acc.x, o);
        acc.y += __shfl_xor(acc.y, o);
        acc.z += __shfl_xor(acc.z, o);
        acc.w += __shfl_xor(acc.w, o);
    }

    if (eg == 0) {
        float inv = 1.f / (Z + 1e-16f);
        const float4 bv = *(const float4*)(bias + 4 * cg);
        float4 o4;
        o4.x = acc.x * inv + bv.x;
        o4.y = acc.y * inv + bv.y;
        o4.z = acc.z * inv + bv.z;
        o4.w = acc.w * inv + bv.w;
        if (do_relu) {
            o4.x = fmaxf(o4.x, 0.f); o4.y = fmaxf(o4.y, 0.f);
            o4.z = fmaxf(o4.z, 0.f); o4.w = fmaxf(o4.w, 0.f);
        }
        *(float4*)(OUT + (size_t)wid * 64 + 4 * cg) = o4;
    }
}

// ---------------------------------------------------------------------------

static inline size_t align256(size_t x) { return (x + 255) & ~(size_t)255; }

extern "C" void kernel_launch(void* const* d_in, const int* in_sizes, int n_in,
                              void* d_out, int out_size, void* d_ws, size_t ws_size,
                              hipStream_t stream) {
    const float* x    = (const float*)d_in[0];
    const int*   esrc = (const int*)d_in[1];
    const int*   edst = (const int*)d_in[2];
    const int E = in_sizes[1];
    const int N = in_sizes[0] / 128;

    const float* W0 = (const float*)d_in[3];
    const float* as0 = (const float*)d_in[4];
    const float* ad0 = (const float*)d_in[5];
    const float* b0 = (const float*)d_in[6];
    const float* W1 = (const float*)d_in[7];
    const float* as1 = (const float*)d_in[8];
    const float* ad1 = (const float*)d_in[9];
    const float* b1 = (const float*)d_in[10];
    const float* W2 = (const float*)d_in[11];
    const float* as2 = (const float*)d_in[12];
    const float* ad2 = (const float*)d_in[13];
    const float* b2 = (const float*)d_in[14];

    // workspace layout
    char* p = (char*)d_ws;
    int* cnt       = (int*)p; p += align256((size_t)N * 4);
    int* rowptr    = (int*)p; p += align256((size_t)(N + 1) * 4);
    int* fill      = (int*)p; p += align256((size_t)N * 4);
    int* blocksums = (int*)p; p += align256(1024 * 4);
    int* csr_src   = (int*)p; p += align256((size_t)(E + N) * 4);
    float* h  = (float*)p; p += align256((size_t)N * 64 * 4);
    float* s  = (float*)p; p += align256((size_t)N * 4);
    float* d  = (float*)p; p += align256((size_t)N * 4);
    float* XA = (float*)p; p += align256((size_t)N * 64 * 4);
    float* XB = (float*)p; p += align256((size_t)N * 64 * 4);
    float* out = (float*)d_out;

    // ---- CSR build (once; shared by all 3 layers) ----
    int nscan = (N + 255) / 256;  // 196 blocks <= 1024
    init_cnt_kernel<<<(N + 255) / 256, 256, 0, stream>>>(cnt, N);
    count_kernel<<<(E + 255) / 256, 256, 0, stream>>>(edst, cnt, E);
    scan_partial_kernel<<<nscan, 256, 0, stream>>>(cnt, blocksums, N);
    scan_blocksums_kernel<<<1, 1024, 0, stream>>>(blocksums, rowptr, nscan, N);
    scan_write_kernel<<<nscan, 256, 0, stream>>>(cnt, blocksums, rowptr, fill, N);
    scatter_kernel<<<(E + N + 255) / 256, 256, 0, stream>>>(esrc, edst, fill, csr_src, E, N);

    int gemm_grid = (N + 63) / 64;
    int agg_grid  = (N + 3) / 4;  // 4 waves per 256-thread block, 1 wave per node

    // ---- layer 0: 128 -> 64, relu ----
    gemm_feat_kernel<128><<<gemm_grid, 256, 0, stream>>>(x, W0, as0, ad0, h, s, d, N);
    gat_aggregate_kernel<<<agg_grid, 256, 0, stream>>>(h, s, d, rowptr, csr_src, b0, XA, N, 1);

    // ---- layer 1: 64 -> 64, relu ----
    gemm_feat_kernel<64><<<gemm_grid, 256, 0, stream>>>(XA, W1, as1, ad1, h, s, d, N);
    gat_aggregate_kernel<<<agg_grid, 256, 0, stream>>>(h, s, d, rowptr, csr_src, b1, XB, N, 1);

    // ---- layer 2: 64 -> 64, no relu ----
    gemm_feat_kernel<64><<<gemm_grid, 256, 0, stream>>>(XB, W2, as2, ad2, h, s, d, N);
    gat_aggregate_kernel<<<agg_grid, 256, 0, stream>>>(h, s, d, rowptr, csr_src, b2, out, N, 0);
}

// Round 5
// 299.482 us; speedup vs baseline: 2.1371x; 1.1960x over previous
//
#include <hip/hip_runtime.h>
#include <math.h>

#define WAVE 64
#define NEG_SLOPE 0.2f

// ---------------------------------------------------------------------------
// CSR build via two-level counting sort (bucket = 128 consecutive dst nodes).
// Replaces the random-scatter build: all global writes are either coalesced
// bursts (A3) or confined to a small per-block region (B) -> no 64B-line
// write amplification (R4 profile: 54.6 MB writes for 3.4 MB payload).
// ---------------------------------------------------------------------------

// A1: per-block LDS histogram of dst>>7, flushed with one atomic per bucket.
__global__ __launch_bounds__(256) void bucket_count_kernel(
    const int* __restrict__ dst, int* __restrict__ gcnt, int e, int nb) {
    extern __shared__ int cnt[];
    for (int b = threadIdx.x; b < nb; b += 256) cnt[b] = 0;
    __syncthreads();
    int base = blockIdx.x * 4096;
#pragma unroll
    for (int k = 0; k < 16; ++k) {
        int i = base + k * 256 + threadIdx.x;
        if (i < e) atomicAdd(&cnt[dst[i] >> 7], 1);
    }
    __syncthreads();
    for (int b = threadIdx.x; b < nb; b += 256) {
        int c = cnt[b];
        if (c) atomicAdd(&gcnt[b], c);
    }
}

// A2: one block scans bucket counts -> boff (exclusive), gfill copy; totals.
__global__ __launch_bounds__(512) void bucket_scan_kernel(
    const int* __restrict__ gcnt, int* __restrict__ boff, int* __restrict__ gfill,
    int* __restrict__ rowptr, int nb, int e, int n) {
    __shared__ int sh[512];
    int t = threadIdx.x;
    int v = (t < nb) ? gcnt[t] : 0;
    sh[t] = v;
    __syncthreads();
    for (int o = 1; o < 512; o <<= 1) {
        int u = (t >= o) ? sh[t - o] : 0;
        __syncthreads();
        sh[t] += u;
        __syncthreads();
    }
    if (t < nb) { int ex = sh[t] - v; boff[t] = ex; gfill[t] = ex; }
    if (t == 0) { boff[nb] = e; rowptr[n] = e + n; }
}

// A3: binned placement. Per 4096-edge block: LDS count -> reserve per-bucket
// region (one atomic per bucket) -> write (src,dst) pairs; edges of the same
// bucket from this block land contiguously (~10-edge bursts).
__global__ __launch_bounds__(256) void bucket_place_kernel(
    const int* __restrict__ src, const int* __restrict__ dst,
    int* __restrict__ gfill, int2* __restrict__ binned, int e, int nb) {
    extern __shared__ int lds[];
    int* cnt = lds;        // [nb]
    int* bas = lds + nb;   // [nb]
    for (int b = threadIdx.x; b < nb; b += 256) cnt[b] = 0;
    __syncthreads();
    int base = blockIdx.x * 4096;
#pragma unroll
    for (int k = 0; k < 16; ++k) {
        int i = base + k * 256 + threadIdx.x;
        if (i < e) atomicAdd(&cnt[dst[i] >> 7], 1);
    }
    __syncthreads();
    for (int b = threadIdx.x; b < nb; b += 256) {
        int c = cnt[b];
        bas[b] = c ? atomicAdd(&gfill[b], c) : 0;
        cnt[b] = 0;
    }
    __syncthreads();
#pragma unroll
    for (int k = 0; k < 16; ++k) {
        int i = base + k * 256 + threadIdx.x;
        if (i < e) {
            int d = dst[i];
            int bk = d >> 7;
            int r = atomicAdd(&cnt[bk], 1);
            binned[bas[bk] + r] = make_int2(src[i], d);
        }
    }
}

// B: one block per bucket -> exact per-node CSR. Self loop at slot 0.
// All csr_src writes fall in a ~9KB region -> merged in one XCD's L2.
__global__ __launch_bounds__(256) void bucket_build_kernel(
    const int2* __restrict__ binned, const int* __restrict__ boff,
    int* __restrict__ csr_src, int* __restrict__ rowptr, int n) {
    __shared__ int cnt[128], off[128], pcnt[128];
    int b = blockIdx.x;
    int t = threadIdx.x;
    int nodeBase = b << 7;
    int nc = min(128, n - nodeBase);
    int e0 = boff[b], e1 = boff[b + 1];
    int ne = e1 - e0;
    if (t < 128) { cnt[t] = 1; pcnt[t] = 1; }  // self-loop reserves slot 0
    __syncthreads();
    for (int i = t; i < ne; i += 256)
        atomicAdd(&cnt[binned[e0 + i].y - nodeBase], 1);
    __syncthreads();
    if (t < 128) off[t] = cnt[t];
    __syncthreads();
    for (int o = 1; o < 128; o <<= 1) {
        int u = (t >= o && t < 128) ? off[t - o] : 0;
        __syncthreads();
        if (t < 128) off[t] += u;
        __syncthreads();
    }
    if (t < 128) off[t] -= cnt[t];  // exclusive
    __syncthreads();
    int csrBase = e0 + nodeBase;  // earlier buckets' edges + their self loops
    if (t < nc) {
        rowptr[nodeBase + t] = csrBase + off[t];
        csr_src[csrBase + off[t]] = nodeBase + t;  // self loop
    }
    for (int i = t; i < ne; i += 256) {
        int2 p = binned[e0 + i];
        int loc = p.y - nodeBase;
        int r = atomicAdd(&pcnt[loc], 1);
        csr_src[csrBase + off[loc] + r] = p.x;
    }
}

// ---------------------------------------------------------------------------
// Feature transform: H = X @ W ;  S = H . a_src ;  D = H . a_dst
// Register-tiled: 256 threads = 16x16, 4x4 micro-tile per thread.
// ---------------------------------------------------------------------------

template <int K>
__global__ __launch_bounds__(256) void gemm_feat_kernel(
    const float* __restrict__ X, const float* __restrict__ W,
    const float* __restrict__ a_s, const float* __restrict__ a_d,
    float* __restrict__ H, float* __restrict__ S, float* __restrict__ D, int n) {
    constexpr int LSTR = 68;  // padded row stride (dwords)
    __shared__ float Xs[64 * LSTR];
    __shared__ float Ws[64 * LSTR];
    int t = threadIdx.x;
    int tx = t & 15;   // col group: cols 4tx..4tx+3
    int ty = t >> 4;   // row group: rows 4ty..4ty+3
    int base = blockIdx.x * 64;
    float acc[4][4] = {};

    int q = t & 3;        // staging quarter
    int srow = t >> 2;    // staging row 0..63

    for (int k0 = 0; k0 < K; k0 += 64) {
        int grow = base + srow;
#pragma unroll
        for (int j = 0; j < 4; ++j) {
            int c = 16 * j + 4 * q;
            float4 v = make_float4(0.f, 0.f, 0.f, 0.f);
            if (grow < n) v = *(const float4*)(X + (size_t)grow * K + k0 + c);
            *(float4*)(Xs + srow * LSTR + c) = v;
            float4 w = *(const float4*)(W + (size_t)(k0 + srow) * 64 + c);
            *(float4*)(Ws + srow * LSTR + c) = w;
        }
        __syncthreads();
#pragma unroll 8
        for (int kk = 0; kk < 64; ++kk) {
            float4 wv = *(const float4*)(Ws + kk * LSTR + 4 * tx);
#pragma unroll
            for (int i = 0; i < 4; ++i) {
                float xv = Xs[(4 * ty + i) * LSTR + kk];
                acc[i][0] = fmaf(xv, wv.x, acc[i][0]);
                acc[i][1] = fmaf(xv, wv.y, acc[i][1]);
                acc[i][2] = fmaf(xv, wv.z, acc[i][2]);
                acc[i][3] = fmaf(xv, wv.w, acc[i][3]);
            }
        }
        __syncthreads();
    }

    const float4 av_s = *(const float4*)(a_s + 4 * tx);
    const float4 av_d = *(const float4*)(a_d + 4 * tx);
#pragma unroll
    for (int i = 0; i < 4; ++i) {
        int row = base + 4 * ty + i;
        bool ok = row < n;
        if (ok) {
            float4 hv = make_float4(acc[i][0], acc[i][1], acc[i][2], acc[i][3]);
            *(float4*)(H + (size_t)row * 64 + 4 * tx) = hv;
        }
        float ps = acc[i][0] * av_s.x + acc[i][1] * av_s.y +
                   acc[i][2] * av_s.z + acc[i][3] * av_s.w;
        float pd = acc[i][0] * av_d.x + acc[i][1] * av_d.y +
                   acc[i][2] * av_d.z + acc[i][3] * av_d.w;
        for (int o = 1; o < 16; o <<= 1) {
            ps += __shfl_xor(ps, o);
            pd += __shfl_xor(pd, o);
        }
        if (tx == 0 && ok) { S[row] = ps; D[row] = pd; }
    }
}

// ---------------------------------------------------------------------------
// GAT aggregation, one wave per dst node.
// Logit phase: lane = edge (chunk of 64), online softmax.
// Row phase: 4 edge-subgroups x 16 channel-groups, float4 gathers.
// ---------------------------------------------------------------------------

__global__ __launch_bounds__(256) void gat_aggregate_kernel(
    const float* __restrict__ H, const float* __restrict__ S,
    const float* __restrict__ D, const int* __restrict__ rowptr,
    const int* __restrict__ csr_src, const float* __restrict__ bias,
    float* __restrict__ OUT, int n, int do_relu) {
    int wid  = (blockIdx.x * blockDim.x + threadIdx.x) >> 6;
    int lane = threadIdx.x & 63;
    if (wid >= n) return;
    int eg = lane >> 4;   // edge subgroup 0..3
    int cg = lane & 15;   // channel group: channels 4cg..4cg+3
    int start = rowptr[wid];
    int end   = rowptr[wid + 1];
    float d_i = D[wid];

    float M = -INFINITY;
    float Z = 0.f;
    float4 acc = make_float4(0.f, 0.f, 0.f, 0.f);

    for (int cb = start; cb < end; cb += WAVE) {
        int j = cb + lane;
        int srcj = 0;
        float ej = -INFINITY;
        if (j < end) {
            srcj = csr_src[j];
            float e = S[srcj] + d_i;
            ej = (e > 0.f) ? e : NEG_SLOPE * e;
        }
        float mc = ej;
        for (int o = 32; o; o >>= 1) mc = fmaxf(mc, __shfl_xor(mc, o));
        float newM = fmaxf(M, mc);
        float scale = expf(M - newM);  // first iter: exp(-inf)=0
        float wj = (j < end) ? expf(ej - newM) : 0.f;
        float zc = wj;
        for (int o = 32; o; o >>= 1) zc += __shfl_xor(zc, o);
        Z = Z * scale + zc;
        acc.x *= scale; acc.y *= scale; acc.z *= scale; acc.w *= scale;
        M = newM;

        int nch = min(WAVE, end - cb);
        for (int c0 = 0; c0 < nch; c0 += 4) {
            int c = c0 + eg;
            float w  = __shfl(wj, c);
            int   sv = __shfl(srcj, c);
            if (c < nch) {
                float4 hv = *(const float4*)(H + (size_t)sv * 64 + 4 * cg);
                acc.x = fmaf(w, hv.x, acc.x);
                acc.y = fmaf(w, hv.y, acc.y);
                acc.z = fmaf(w, hv.z, acc.z);
                acc.w = fmaf(w, hv.w, acc.w);
            }
        }
    }

    for (int o = 16; o < 64; o <<= 1) {
        acc.x += __shfl_xor(acc.x, o);
        acc.y += __shfl_xor(acc.y, o);
        acc.z += __shfl_xor(acc.z, o);
        acc.w += __shfl_xor(acc.w, o);
    }

    if (eg == 0) {
        float inv = 1.f / (Z + 1e-16f);
        const float4 bv = *(const float4*)(bias + 4 * cg);
        float4 o4;
        o4.x = acc.x * inv + bv.x;
        o4.y = acc.y * inv + bv.y;
        o4.z = acc.z * inv + bv.z;
        o4.w = acc.w * inv + bv.w;
        if (do_relu) {
            o4.x = fmaxf(o4.x, 0.f); o4.y = fmaxf(o4.y, 0.f);
            o4.z = fmaxf(o4.z, 0.f); o4.w = fmaxf(o4.w, 0.f);
        }
        *(float4*)(OUT + (size_t)wid * 64 + 4 * cg) = o4;
    }
}

// ---------------------------------------------------------------------------

static inline size_t align256(size_t x) { return (x + 255) & ~(size_t)255; }

extern "C" void kernel_launch(void* const* d_in, const int* in_sizes, int n_in,
                              void* d_out, int out_size, void* d_ws, size_t ws_size,
                              hipStream_t stream) {
    const float* x    = (const float*)d_in[0];
    const int*   esrc = (const int*)d_in[1];
    const int*   edst = (const int*)d_in[2];
    const int E = in_sizes[1];
    const int N = in_sizes[0] / 128;

    const float* W0 = (const float*)d_in[3];
    const float* as0 = (const float*)d_in[4];
    const float* ad0 = (const float*)d_in[5];
    const float* b0 = (const float*)d_in[6];
    const float* W1 = (const float*)d_in[7];
    const float* as1 = (const float*)d_in[8];
    const float* ad1 = (const float*)d_in[9];
    const float* b1 = (const float*)d_in[10];
    const float* W2 = (const float*)d_in[11];
    const float* as2 = (const float*)d_in[12];
    const float* ad2 = (const float*)d_in[13];
    const float* b2 = (const float*)d_in[14];

    const int NB = (N + 127) >> 7;  // buckets of 128 nodes (<=512 for scan)

    // workspace layout
    char* p = (char*)d_ws;
    int* gcnt    = (int*)p; p += align256((size_t)(NB + 1) * 4);
    int* boff    = (int*)p; p += align256((size_t)(NB + 1) * 4);
    int* gfill   = (int*)p; p += align256((size_t)(NB + 1) * 4);
    int* rowptr  = (int*)p; p += align256((size_t)(N + 1) * 4);
    int* csr_src = (int*)p; p += align256((size_t)(E + N) * 4);
    float* h  = (float*)p; p += align256((size_t)N * 64 * 4);
    float* s  = (float*)p; p += align256((size_t)N * 4);
    float* d  = (float*)p; p += align256((size_t)N * 4);
    float* XA = (float*)p; p += align256((size_t)N * 64 * 4);
    float* XB = (float*)p; p += align256((size_t)N * 64 * 4);
    float* out = (float*)d_out;
    int2* binned = (int2*)XA;  // alias: binned (8E bytes <= 16N*4) dead before XA live

    // ---- CSR build (two-level counting sort) ----
    int nchunk = (E + 4095) / 4096;
    hipMemsetAsync(gcnt, 0, (size_t)(NB + 1) * 4, stream);
    bucket_count_kernel<<<nchunk, 256, NB * 4, stream>>>(edst, gcnt, E, NB);
    bucket_scan_kernel<<<1, 512, 0, stream>>>(gcnt, boff, gfill, rowptr, NB, E, N);
    bucket_place_kernel<<<nchunk, 256, 2 * NB * 4, stream>>>(esrc, edst, gfill, binned, E, NB);
    bucket_build_kernel<<<NB, 256, 0, stream>>>(binned, boff, csr_src, rowptr, N);

    int gemm_grid = (N + 63) / 64;
    int agg_grid  = (N + 3) / 4;  // 4 waves per 256-thread block, 1 wave per node

    // ---- layer 0: 128 -> 64, relu ----
    gemm_feat_kernel<128><<<gemm_grid, 256, 0, stream>>>(x, W0, as0, ad0, h, s, d, N);
    gat_aggregate_kernel<<<agg_grid, 256, 0, stream>>>(h, s, d, rowptr, csr_src, b0, XA, N, 1);

    // ---- layer 1: 64 -> 64, relu ----
    gemm_feat_kernel<64><<<gemm_grid, 256, 0, stream>>>(XA, W1, as1, ad1, h, s, d, N);
    gat_aggregate_kernel<<<agg_grid, 256, 0, stream>>>(h, s, d, rowptr, csr_src, b1, XB, N, 1);

    // ---- layer 2: 64 -> 64, no relu ----
    gemm_feat_kernel<64><<<gemm_grid, 256, 0, stream>>>(XB, W2, as2, ad2, h, s, d, N);
    gat_aggregate_kernel<<<agg_grid, 256, 0, stream>>>(h, s, d, rowptr, csr_src, b2, out, N, 0);
}